// Round 4
// baseline (360.410 us; speedup 1.0000x reference)
//
#include <hip/hip_runtime.h>
#include <stdint.h>
#include <math.h>

typedef unsigned short u16;
typedef short bf16x8 __attribute__((ext_vector_type(8)));
typedef unsigned short u16x8 __attribute__((ext_vector_type(8)));
typedef float f32x4 __attribute__((ext_vector_type(4)));

#define LOG2E 1.4426950408889634f

__device__ __forceinline__ float bf2f(u16 u) {
  union { unsigned int i; float f; } v; v.i = ((unsigned int)u) << 16; return v.f;
}
__device__ __forceinline__ u16 f2bf(float f) {
  union { float ff; unsigned int i; } v; v.ff = f;
  unsigned int x = v.i;
  return (u16)((x + 0x7FFFu + ((x >> 16) & 1u)) >> 16);
}

// ---------------------------------------------------------------------------
// Per-batch transpose+convert: VT[b][n][k] = (bf16)V[b][k][n]. 64x64 tiles.
// ---------------------------------------------------------------------------
__global__ __launch_bounds__(256)
void transcvt_v(const float* __restrict__ V, u16* __restrict__ VT, int S, int E)
{
  __shared__ u16 t[64][72];
  const int b = blockIdx.z;
  const float* Vb = V + (long)b * S * E;
  u16* VTb = VT + (long)b * S * E;
  const int k0 = blockIdx.x * 64, n0 = blockIdx.y * 64;
  const int tid = threadIdx.x;
#pragma unroll
  for (int p = 0; p < 2; p++) {
    int kk = p * 32 + (tid >> 3);
    int nn = (tid & 7) * 8;
    f32x4 a = *(const f32x4*)&Vb[(long)(k0 + kk) * E + n0 + nn];
    f32x4 c = *(const f32x4*)&Vb[(long)(k0 + kk) * E + n0 + nn + 4];
#pragma unroll
    for (int j = 0; j < 4; j++) { t[nn + j][kk] = f2bf(a[j]); t[nn + 4 + j][kk] = f2bf(c[j]); }
  }
  __syncthreads();
#pragma unroll
  for (int p = 0; p < 2; p++) {
    int nn = p * 32 + (tid >> 3);
    int kk = (tid & 7) * 8;
    u16x8 u;
#pragma unroll
    for (int j = 0; j < 8; j++) u[j] = t[nn][kk + j];
    *(u16x8*)&VTb[(long)(n0 + nn) * S + k0 + kk] = u;
  }
}

// ---------------------------------------------------------------------------
// Pipelined GEMM (BT layout): C[g][n] = scale*sum_k A[g][k]*B[n][k] (+mask)
//  SRC_F32: operands fp32 (converted to bf16 during staging) vs bf16 direct.
//  Fragment-packed LDS (conflict-free ds_read_b128), double-buffered,
//  ONE barrier per k-step; global loads for k+1 issued before MFMA of k and
//  consumed by ds_write after MFMA -> prefetch latency hidden behind compute,
//  and (VGPR staging) the barrier does NOT drain vmcnt for the prefetch.
// 128x128 tile, 4 waves, 4x4 16x16x32 MFMA acc, BK=32, LDS=32KB.
// ---------------------------------------------------------------------------
template<int ASRC_F32, int BSRC_F32, int HASMASK, int COUT>
__global__ __launch_bounds__(256, 2)
void gemm_pl(const void* __restrict__ A_, int lda, long aRowOff,
             const void* __restrict__ B_, int ldb, long bBatchStride,
             void* __restrict__ Cp, int ldc, long cRowOff,
             const float* __restrict__ maskf,
             int K, float scale, long g0, int S)
{
  const int tid  = threadIdx.x;
  const int lane = tid & 63;
  const int wave = tid >> 6;
  const long gTile = g0 + (long)blockIdx.y * 128;
  const int  b     = (int)(gTile / S);
  const int  nTile = blockIdx.x * 128;

  __shared__ u16 lds[16384];   // 2 bufs x (A 4096 | B 4096) u16

  const float* Af = (const float*)A_ + (gTile - aRowOff) * (long)lda;
  const u16*   Ab = (const u16*)A_   + (gTile - aRowOff) * (long)lda;
  const float* Bf = (const float*)B_ + (long)b * bBatchStride;
  const u16*   Bb = (const u16*)B_   + (long)b * bBatchStride;

  // staging geometry: thread handles subtile slots (wave, lane) and (wave+4, lane)
  // slot (ss, l): row = ss*16 + (l&15), col8 = (l>>4)*8, LDS idx = ss*512 + l*8
  const int row0 = wave * 16 + (lane & 15);
  const int col8 = (lane >> 4) * 8;
  const long aoff0 = (long)row0 * lda + col8;
  const long aoff1 = aoff0 + (long)64 * lda;
  const long boff0 = (long)(nTile + row0) * ldb + col8;
  const long boff1 = boff0 + (long)64 * ldb;
  const int idx0 = wave * 512 + lane * 8;     // A slot 0
  const int idx1 = idx0 + 2048;               // A slot 1 (ss+4)

  f32x4 acc[4][4];
#pragma unroll
  for (int i = 0; i < 4; i++)
#pragma unroll
    for (int j = 0; j < 4; j++) acc[i][j] = (f32x4){0.f, 0.f, 0.f, 0.f};

  const int qmi = (wave >> 1) * 4;
  const int qni = (wave & 1) * 4;

  // prefetch registers
  f32x4 fa0a, fa0b, fa1a, fa1b, fb0a, fb0b, fb1a, fb1b;
  u16x8 ua0, ua1, ub0, ub1;

#define LOAD_STEP(k0)                                                        \
  do {                                                                       \
    if (ASRC_F32) {                                                          \
      fa0a = *(const f32x4*)&Af[aoff0 + (k0)];                               \
      fa0b = *(const f32x4*)&Af[aoff0 + (k0) + 4];                           \
      fa1a = *(const f32x4*)&Af[aoff1 + (k0)];                               \
      fa1b = *(const f32x4*)&Af[aoff1 + (k0) + 4];                           \
    } else {                                                                 \
      ua0 = *(const u16x8*)&Ab[aoff0 + (k0)];                                \
      ua1 = *(const u16x8*)&Ab[aoff1 + (k0)];                                \
    }                                                                        \
    if (BSRC_F32) {                                                          \
      fb0a = *(const f32x4*)&Bf[boff0 + (k0)];                               \
      fb0b = *(const f32x4*)&Bf[boff0 + (k0) + 4];                           \
      fb1a = *(const f32x4*)&Bf[boff1 + (k0)];                               \
      fb1b = *(const f32x4*)&Bf[boff1 + (k0) + 4];                           \
    } else {                                                                 \
      ub0 = *(const u16x8*)&Bb[boff0 + (k0)];                                \
      ub1 = *(const u16x8*)&Bb[boff1 + (k0)];                                \
    }                                                                        \
  } while (0)

#define WRITE_STEP(bufOff)                                                   \
  do {                                                                       \
    if (ASRC_F32) {                                                          \
      u16x8 w0, w1;                                                          \
      _Pragma("unroll")                                                      \
      for (int j = 0; j < 4; j++) {                                          \
        w0[j] = f2bf(fa0a[j]); w0[4 + j] = f2bf(fa0b[j]);                    \
        w1[j] = f2bf(fa1a[j]); w1[4 + j] = f2bf(fa1b[j]);                    \
      }                                                                      \
      *(u16x8*)&lds[(bufOff) + idx0] = w0;                                   \
      *(u16x8*)&lds[(bufOff) + idx1] = w1;                                   \
    } else {                                                                 \
      *(u16x8*)&lds[(bufOff) + idx0] = ua0;                                  \
      *(u16x8*)&lds[(bufOff) + idx1] = ua1;                                  \
    }                                                                        \
    if (BSRC_F32) {                                                          \
      u16x8 w0, w1;                                                          \
      _Pragma("unroll")                                                      \
      for (int j = 0; j < 4; j++) {                                          \
        w0[j] = f2bf(fb0a[j]); w0[4 + j] = f2bf(fb0b[j]);                    \
        w1[j] = f2bf(fb1a[j]); w1[4 + j] = f2bf(fb1b[j]);                    \
      }                                                                      \
      *(u16x8*)&lds[(bufOff) + 4096 + idx0] = w0;                            \
      *(u16x8*)&lds[(bufOff) + 4096 + idx1] = w1;                            \
    } else {                                                                 \
      *(u16x8*)&lds[(bufOff) + 4096 + idx0] = ub0;                           \
      *(u16x8*)&lds[(bufOff) + 4096 + idx1] = ub1;                           \
    }                                                                        \
  } while (0)

  const int Ksteps = K / 32;
  LOAD_STEP(0);
  WRITE_STEP(0);

  int cb = 0;
  for (int i = 0; i < Ksteps; ++i) {
    __syncthreads();
    const int cOff = cb * 8192;
    if (i + 1 < Ksteps) LOAD_STEP((i + 1) * 32);   // prefetch: in flight over MFMA
    bf16x8 af[4], bfr[4];
#pragma unroll
    for (int rt = 0; rt < 4; rt++)
      af[rt] = *(const bf16x8*)&lds[cOff + (qmi + rt) * 512 + lane * 8];
#pragma unroll
    for (int ct = 0; ct < 4; ct++)
      bfr[ct] = *(const bf16x8*)&lds[cOff + 4096 + (qni + ct) * 512 + lane * 8];
#pragma unroll
    for (int rt = 0; rt < 4; rt++)
#pragma unroll
      for (int ct = 0; ct < 4; ct++)
        acc[rt][ct] = __builtin_amdgcn_mfma_f32_16x16x32_bf16(af[rt], bfr[ct], acc[rt][ct], 0, 0, 0);
    if (i + 1 < Ksteps) WRITE_STEP((cb ^ 1) * 8192);
    cb ^= 1;
  }
#undef LOAD_STEP
#undef WRITE_STEP

  // epilogue: C/D layout col = lane&15, row = (lane>>4)*4 + reg  (verified)
  const int qm = (wave >> 1) * 64;
  const int qn = (wave & 1) * 64;
  const int lm16 = lane & 15;
  const int lr = (lane >> 4) * 4;
#pragma unroll
  for (int rt = 0; rt < 4; rt++) {
#pragma unroll
    for (int ct = 0; ct < 4; ct++) {
      long gr = gTile + qm + rt * 16 + lr;
      int  cc = nTile + qn + ct * 16 + lm16;
#pragma unroll
      for (int i = 0; i < 4; i++) {
        float v = acc[rt][ct][i] * scale;
        if (HASMASK) v += maskf[(gr + i) * (long)ldc + cc];
        if (COUT == 0)
          ((u16*)Cp)[(gr + i - cRowOff) * (long)ldc + cc] = f2bf(v);
        else
          ((float*)Cp)[(gr + i - cRowOff) * (long)ldc + cc] = v;
      }
    }
  }
}

// ---------------------------------------------------------------------------
// Row softmax in place on bf16 rows of length ncols == 2048 == 256*8
// ---------------------------------------------------------------------------
__global__ __launch_bounds__(256)
void softmax_rows(u16* __restrict__ Sbuf, int ncols)
{
  const long row = blockIdx.x;
  u16* rp = Sbuf + row * (long)ncols;
  const int tid = threadIdx.x;

  u16x8 u = *(const u16x8*)&rp[tid * 8];
  float x[8];
  float m = -3.0e38f;
#pragma unroll
  for (int i = 0; i < 8; i++) { x[i] = bf2f(u[i]); m = fmaxf(m, x[i]); }
#pragma unroll
  for (int off = 32; off; off >>= 1) m = fmaxf(m, __shfl_xor(m, off, 64));
  __shared__ float redm[4];
  if ((tid & 63) == 0) redm[tid >> 6] = m;
  __syncthreads();
  m = fmaxf(fmaxf(redm[0], redm[1]), fmaxf(redm[2], redm[3]));

  float e[8];
  float s = 0.f;
#pragma unroll
  for (int i = 0; i < 8; i++) { e[i] = exp2f((x[i] - m) * LOG2E); s += e[i]; }
#pragma unroll
  for (int off = 32; off; off >>= 1) s += __shfl_xor(s, off, 64);
  __shared__ float reds[4];
  if ((tid & 63) == 0) reds[tid >> 6] = s;
  __syncthreads();
  s = reds[0] + reds[1] + reds[2] + reds[3];

  float inv = 1.0f / s;
  u16x8 o;
#pragma unroll
  for (int i = 0; i < 8; i++) o[i] = f2bf(e[i] * inv);
  *(u16x8*)&rp[tid * 8] = o;
}

extern "C" void kernel_launch(void* const* d_in, const int* in_sizes, int n_in,
                              void* d_out, int out_size, void* d_ws, size_t ws_size,
                              hipStream_t stream)
{
  const float* Q    = (const float*)d_in[0];
  const float* Km   = (const float*)d_in[1];
  const float* V    = (const float*)d_in[2];
  const float* mask = (const float*)d_in[3];
  float* out = (float*)d_out;

  const long qsz = in_sizes[0];          // B*S*E
  const long msz = in_sizes[3];          // B*S*S
  const long E = 1024;
  const long S = (msz / qsz) * E;        // 2048
  const long B = qsz / (S * E);          // 4
  const long G = B * S;
  const float scale = 1.0f / sqrtf((float)E);

  // ws plan: VT (bf16, B*E*S) + score strip (bf16, Rmax*S)
  const size_t vtBytes  = (size_t)qsz * 2;   // 16.8 MB
  const size_t rowBytes = (size_t)S * 2;
  char* w = (char*)d_ws;
  u16* VTb = (u16*)w;  w += vtBytes;
  size_t avail = (ws_size > vtBytes) ? ws_size - vtBytes : 0;
  long Rmax = (long)((avail / rowBytes) / 128) * 128;
  if (Rmax > G) Rmax = G;
  if (Rmax < 128) Rmax = 128;   // ws is known >= ~50 MB from prior rounds
  u16* Sbuf = (u16*)w;

  transcvt_v<<<dim3(S / 64, E / 64, B), 256, 0, stream>>>(V, VTb, (int)S, (int)E);

  for (long g0 = 0; g0 < G; g0 += Rmax) {
    const long R = (G - g0 < Rmax) ? (G - g0) : Rmax;
    // 1) scores = scale*Q K^T + mask   (fp32 in, bf16 out, cvt fused in staging)
    gemm_pl<1, 1, 1, 0><<<dim3(S / 128, R / 128), 256, 0, stream>>>(
        Q, (int)E, 0L, Km, (int)E, S * E,
        Sbuf, (int)S, g0, mask, (int)E, scale, g0, (int)S);
    // 2) softmax rows in place
    softmax_rows<<<dim3(R), 256, 0, stream>>>(Sbuf, (int)S);
    // 3) out = P @ V   (bf16 in, fp32 out)
    gemm_pl<0, 0, 0, 1><<<dim3(E / 128, R / 128), 256, 0, stream>>>(
        Sbuf, (int)S, g0, VTb, (int)S, E * S,
        out, (int)E, 0L, nullptr, (int)S, 1.0f, g0, (int)S);
  }
}

// Round 5
// 319.448 us; speedup vs baseline: 1.1282x; 1.1282x over previous
//
#include <hip/hip_runtime.h>
#include <stdint.h>
#include <math.h>

typedef unsigned short u16;
typedef short bf16x8 __attribute__((ext_vector_type(8)));
typedef unsigned short u16x8 __attribute__((ext_vector_type(8)));
typedef unsigned short u16x4 __attribute__((ext_vector_type(4)));
typedef float f32x4 __attribute__((ext_vector_type(4)));

#define LOG2E 1.4426950408889634f

__device__ __forceinline__ float bf2f(u16 u) {
  union { unsigned int i; float f; } v; v.i = ((unsigned int)u) << 16; return v.f;
}
__device__ __forceinline__ u16 f2bf(float f) {
  union { float ff; unsigned int i; } v; v.ff = f;
  unsigned int x = v.i;
  return (u16)((x + 0x7FFFu + ((x >> 16) & 1u)) >> 16);
}

// ---------------------------------------------------------------------------
// fp32 -> bf16 flat convert with scale (scale folded into Q here)
// ---------------------------------------------------------------------------
__global__ __launch_bounds__(256)
void cvt_scale(const float* __restrict__ src, u16* __restrict__ dst, long n, float scale)
{
  long i = ((long)blockIdx.x * 256 + threadIdx.x) * 8;
  if (i + 8 > n) return;
  f32x4 a = *(const f32x4*)&src[i];
  f32x4 b = *(const f32x4*)&src[i + 4];
  u16x8 o;
#pragma unroll
  for (int j = 0; j < 4; j++) { o[j] = f2bf(a[j] * scale); o[4 + j] = f2bf(b[j] * scale); }
  *(u16x8*)&dst[i] = o;
}

// ---------------------------------------------------------------------------
// Per-batch transpose+convert: VT[b][n][k] = (bf16)V[b][k][n]. 64x64 tiles.
// ---------------------------------------------------------------------------
__global__ __launch_bounds__(256)
void transcvt_v(const float* __restrict__ V, u16* __restrict__ VT, int S, int E)
{
  __shared__ u16 t[64][72];
  const int b = blockIdx.z;
  const float* Vb = V + (long)b * S * E;
  u16* VTb = VT + (long)b * S * E;
  const int k0 = blockIdx.x * 64, n0 = blockIdx.y * 64;
  const int tid = threadIdx.x;
#pragma unroll
  for (int p = 0; p < 2; p++) {
    int kk = p * 32 + (tid >> 3);
    int nn = (tid & 7) * 8;
    f32x4 a = *(const f32x4*)&Vb[(long)(k0 + kk) * E + n0 + nn];
    f32x4 c = *(const f32x4*)&Vb[(long)(k0 + kk) * E + n0 + nn + 4];
#pragma unroll
    for (int j = 0; j < 4; j++) { t[nn + j][kk] = f2bf(a[j]); t[nn + 4 + j][kk] = f2bf(c[j]); }
  }
  __syncthreads();
#pragma unroll
  for (int p = 0; p < 2; p++) {
    int nn = p * 32 + (tid >> 3);
    int kk = (tid & 7) * 8;
    u16x8 u;
#pragma unroll
    for (int j = 0; j < 8; j++) u[j] = t[nn][kk + j];
    *(u16x8*)&VTb[(long)(n0 + nn) * S + k0 + kk] = u;
  }
}

// ---------------------------------------------------------------------------
// FAST GEMM (bf16 BT): C[g][n] = sum_k A[g][k]*B[n][k]. No mask, no scale
// (both folded elsewhere). R2-style 2-barrier VGPR staging + fragment-packed
// LDS (conflict-free b128) + BK=64: 32 MFMA and 8 in-flight 16B loads per
// thread per barrier pair -> one latency exposure amortized over 2x work.
// 128x128 tile, 4 waves, 4x4 16x16x32 MFMA acc, LDS=32KB.
// ---------------------------------------------------------------------------
template<int COUT>
__global__ __launch_bounds__(256, 3)
void gemm_bf16(const u16* __restrict__ A, int lda, long aRowOff,
               const u16* __restrict__ B, int ldb, long bBatchStride,
               void* __restrict__ Cp, int ldc, long cRowOff,
               int K, long g0, int S)
{
  const int tid  = threadIdx.x;
  const int lane = tid & 63;
  const int wave = tid >> 6;
  const long gTile = g0 + (long)blockIdx.y * 128;
  const int  b     = (int)(gTile / S);
  const int  nTile = blockIdx.x * 128;

  // fragment-packed: subtile (ss in [0,8), ks in [0,2)) holds rows ss*16+(l&15),
  // k = ks*32 + (l>>4)*8 at u16 index ss*1024 + ks*512 + l*8.
  __shared__ u16 As[8192];
  __shared__ u16 Bs[8192];

  const u16* aG = A + (gTile - aRowOff) * (long)lda;
  const u16* bG = B + (long)b * bBatchStride;

  // staging: wave w stages subtiles ss = w*2+p (p=0,1), both ks
  const int r0 = wave * 32 + (lane & 15);
  const int c0 = (lane >> 4) * 8;
  const u16* ag = aG + (long)r0 * lda + c0;
  const u16* bg = bG + (long)(nTile + r0) * ldb + c0;
  u16* asw = As + wave * 2048 + lane * 8;
  u16* bsw = Bs + wave * 2048 + lane * 8;

  f32x4 acc[4][4];
#pragma unroll
  for (int i = 0; i < 4; i++)
#pragma unroll
    for (int j = 0; j < 4; j++) acc[i][j] = (f32x4){0.f, 0.f, 0.f, 0.f};

  const int qmi = (wave >> 1) * 4;
  const int qni = (wave & 1) * 4;

  for (int k0 = 0; k0 < K; k0 += 64) {
    u16x8 a00 = *(const u16x8*)&ag[k0];
    u16x8 a01 = *(const u16x8*)&ag[k0 + 32];
    u16x8 a10 = *(const u16x8*)&ag[(long)16 * lda + k0];
    u16x8 a11 = *(const u16x8*)&ag[(long)16 * lda + k0 + 32];
    u16x8 b00 = *(const u16x8*)&bg[k0];
    u16x8 b01 = *(const u16x8*)&bg[k0 + 32];
    u16x8 b10 = *(const u16x8*)&bg[(long)16 * ldb + k0];
    u16x8 b11 = *(const u16x8*)&bg[(long)16 * ldb + k0 + 32];
    *(u16x8*)&asw[0]    = a00;
    *(u16x8*)&asw[512]  = a01;
    *(u16x8*)&asw[1024] = a10;
    *(u16x8*)&asw[1536] = a11;
    *(u16x8*)&bsw[0]    = b00;
    *(u16x8*)&bsw[512]  = b01;
    *(u16x8*)&bsw[1024] = b10;
    *(u16x8*)&bsw[1536] = b11;
    __syncthreads();

#pragma unroll
    for (int ks = 0; ks < 2; ks++) {
      bf16x8 af[4], bfr[4];
#pragma unroll
      for (int rt = 0; rt < 4; rt++)
        af[rt] = *(const bf16x8*)&As[(qmi + rt) * 1024 + ks * 512 + lane * 8];
#pragma unroll
      for (int ct = 0; ct < 4; ct++)
        bfr[ct] = *(const bf16x8*)&Bs[(qni + ct) * 1024 + ks * 512 + lane * 8];
#pragma unroll
      for (int rt = 0; rt < 4; rt++)
#pragma unroll
        for (int ct = 0; ct < 4; ct++)
          acc[rt][ct] = __builtin_amdgcn_mfma_f32_16x16x32_bf16(af[rt], bfr[ct], acc[rt][ct], 0, 0, 0);
    }
    __syncthreads();
  }

  // epilogue: C/D layout col = lane&15, row = (lane>>4)*4 + reg (verified)
  const int qm = (wave >> 1) * 64;
  const int qn = (wave & 1) * 64;
  const int lm16 = lane & 15;
  const int lr = (lane >> 4) * 4;
#pragma unroll
  for (int rt = 0; rt < 4; rt++) {
#pragma unroll
    for (int ct = 0; ct < 4; ct++) {
      long gr = gTile + qm + rt * 16 + lr;
      int  cc = nTile + qn + ct * 16 + lm16;
#pragma unroll
      for (int i = 0; i < 4; i++) {
        if (COUT == 0)
          ((u16*)Cp)[(gr + i - cRowOff) * (long)ldc + cc] = f2bf(acc[rt][ct][i]);
        else
          ((float*)Cp)[(gr + i - cRowOff) * (long)ldc + cc] = acc[rt][ct][i];
      }
    }
  }
}

// ---------------------------------------------------------------------------
// SLOW fallback GEMM (fp32 sources converted in staging) — only if ws tiny.
// ---------------------------------------------------------------------------
template<int BMODE, int HASMASK, int COUT>
__global__ __launch_bounds__(256, 2)
void gemm_slow(const void* __restrict__ Ap, int lda, long aRowOff,
               const void* __restrict__ Bp, int ldb, long bBatchStride,
               void* __restrict__ Cp, int ldc, long cRowOff,
               const float* __restrict__ maskf,
               int K, float scale, long g0, int S)
{
  const int tid  = threadIdx.x;
  const int lane = tid & 63;
  const int wave = tid >> 6;
  const long gTile = g0 + (long)blockIdx.y * 128;
  const int  b     = (int)(gTile / S);
  const int  nTile = blockIdx.x * 128;

  __shared__ u16 As[128][40];
  __shared__ u16 Bs[128][40];

  const int qm = (wave >> 1) * 64;
  const int qn = (wave & 1) * 64;

  f32x4 acc[4][4];
#pragma unroll
  for (int i = 0; i < 4; i++)
#pragma unroll
    for (int j = 0; j < 4; j++) acc[i][j] = (f32x4){0.f, 0.f, 0.f, 0.f};

  const float* Af = (const float*)Ap + (gTile - aRowOff) * (long)lda;
  const u16*   Ab16 = (const u16*)Ap + (gTile - aRowOff) * (long)lda;
  const float* Bf = (const float*)Bp + (long)b * bBatchStride;

  const int lm = lane & 15;
  const int lk = (lane >> 4) * 8;

  for (int k0 = 0; k0 < K; k0 += 32) {
    if (BMODE == 1) {
      int srow = tid >> 2, scol = (tid & 3) * 8;
#pragma unroll
      for (int p = 0; p < 2; p++) {
        int r = p * 64 + srow;
        *(u16x8*)&As[r][scol] = *(const u16x8*)&Ab16[(long)r * lda + k0 + scol];
      }
    } else {
      int srow = tid >> 3, scol = (tid & 7) * 4;
#pragma unroll
      for (int p = 0; p < 4; p++) {
        int r = p * 32 + srow;
        f32x4 a = *(const f32x4*)&Af[(long)r * lda + k0 + scol];
        u16x4 o;
#pragma unroll
        for (int j = 0; j < 4; j++) o[j] = f2bf(a[j]);
        *(u16x4*)&As[r][scol] = o;
      }
    }
    if (BMODE == 0) {
      int srow = tid >> 3, scol = (tid & 7) * 4;
#pragma unroll
      for (int p = 0; p < 4; p++) {
        int r = p * 32 + srow;
        f32x4 a = *(const f32x4*)&Bf[(long)(nTile + r) * ldb + k0 + scol];
        u16x4 o;
#pragma unroll
        for (int j = 0; j < 4; j++) o[j] = f2bf(a[j]);
        *(u16x4*)&Bs[r][scol] = o;
      }
    }
    __syncthreads();

    bf16x8 af[4], bfr[4];
#pragma unroll
    for (int rt = 0; rt < 4; rt++)
      af[rt] = *(const bf16x8*)&As[qm + rt * 16 + lm][lk];
    if (BMODE == 0) {
#pragma unroll
      for (int ct = 0; ct < 4; ct++)
        bfr[ct] = *(const bf16x8*)&Bs[qn + ct * 16 + lm][lk];
    } else {
#pragma unroll
      for (int ct = 0; ct < 4; ct++) {
        const float* vp = Bf + (long)(k0 + lk) * ldb + nTile + qn + ct * 16 + lm;
#pragma unroll
        for (int j = 0; j < 8; j++) bfr[ct][j] = (short)f2bf(vp[(long)j * ldb]);
      }
    }
#pragma unroll
    for (int rt = 0; rt < 4; rt++)
#pragma unroll
      for (int ct = 0; ct < 4; ct++)
        acc[rt][ct] = __builtin_amdgcn_mfma_f32_16x16x32_bf16(af[rt], bfr[ct], acc[rt][ct], 0, 0, 0);
    __syncthreads();
  }

  const int lr = (lane >> 4) * 4;
#pragma unroll
  for (int rt = 0; rt < 4; rt++) {
#pragma unroll
    for (int ct = 0; ct < 4; ct++) {
      long gr = gTile + qm + rt * 16 + lr;
      int  cc = nTile + qn + ct * 16 + lm;
#pragma unroll
      for (int i = 0; i < 4; i++) {
        float v = acc[rt][ct][i] * scale;
        if (HASMASK) v += maskf[(gr + i) * (long)ldc + cc];
        if (COUT == 0)
          ((u16*)Cp)[(gr + i - cRowOff) * (long)ldc + cc] = f2bf(v);
        else
          ((float*)Cp)[(gr + i - cRowOff) * (long)ldc + cc] = v;
      }
    }
  }
}

// ---------------------------------------------------------------------------
// Row softmax in place, optionally adding fp32 mask first. ncols == 2048.
// ---------------------------------------------------------------------------
template<int HASMASK>
__global__ __launch_bounds__(256)
void softmax_rows(u16* __restrict__ Sbuf, const float* __restrict__ mask,
                  long g0, int ncols)
{
  const long row = blockIdx.x;
  u16* rp = Sbuf + row * (long)ncols;
  const int tid = threadIdx.x;

  u16x8 u = *(const u16x8*)&rp[tid * 8];
  float x[8];
  if (HASMASK) {
    const float* mp = mask + (g0 + row) * (long)ncols + tid * 8;
    f32x4 m0 = *(const f32x4*)&mp[0];
    f32x4 m1 = *(const f32x4*)&mp[4];
#pragma unroll
    for (int i = 0; i < 4; i++) { x[i] = bf2f(u[i]) + m0[i]; x[4 + i] = bf2f(u[4 + i]) + m1[i]; }
  } else {
#pragma unroll
    for (int i = 0; i < 8; i++) x[i] = bf2f(u[i]);
  }
  float m = -3.0e38f;
#pragma unroll
  for (int i = 0; i < 8; i++) m = fmaxf(m, x[i]);
#pragma unroll
  for (int off = 32; off; off >>= 1) m = fmaxf(m, __shfl_xor(m, off, 64));
  __shared__ float redm[4];
  if ((tid & 63) == 0) redm[tid >> 6] = m;
  __syncthreads();
  m = fmaxf(fmaxf(redm[0], redm[1]), fmaxf(redm[2], redm[3]));

  float e[8];
  float s = 0.f;
#pragma unroll
  for (int i = 0; i < 8; i++) { e[i] = exp2f((x[i] - m) * LOG2E); s += e[i]; }
#pragma unroll
  for (int off = 32; off; off >>= 1) s += __shfl_xor(s, off, 64);
  __shared__ float reds[4];
  if ((tid & 63) == 0) reds[tid >> 6] = s;
  __syncthreads();
  s = reds[0] + reds[1] + reds[2] + reds[3];

  float inv = 1.0f / s;
  u16x8 o;
#pragma unroll
  for (int i = 0; i < 8; i++) o[i] = f2bf(e[i] * inv);
  *(u16x8*)&rp[tid * 8] = o;
}

extern "C" void kernel_launch(void* const* d_in, const int* in_sizes, int n_in,
                              void* d_out, int out_size, void* d_ws, size_t ws_size,
                              hipStream_t stream)
{
  const float* Q    = (const float*)d_in[0];
  const float* Km   = (const float*)d_in[1];
  const float* V    = (const float*)d_in[2];
  const float* mask = (const float*)d_in[3];
  float* out = (float*)d_out;

  const long qsz = in_sizes[0];          // B*S*E
  const long msz = in_sizes[3];          // B*S*S
  const long E = 1024;
  const long S = (msz / qsz) * E;        // 2048
  const long B = qsz / (S * E);          // 4
  const long G = B * S;
  const float scale = 1.0f / sqrtf((float)E);

  const size_t convBytes = (size_t)(3 * qsz) * 2;   // Qb + Kb + VTb
  const size_t rowBytes  = (size_t)S * 2;
  char* w = (char*)d_ws;
  size_t avail = ws_size;
  const bool haveConv = (ws_size >= convBytes + 128 * rowBytes);

  u16 *Qb = nullptr, *Kb = nullptr, *VTb = nullptr;
  if (haveConv) {
    Qb  = (u16*)w;  w += (size_t)qsz * 2;
    Kb  = (u16*)w;  w += (size_t)qsz * 2;
    VTb = (u16*)w;  w += (size_t)qsz * 2;
    avail -= convBytes;
  }
  long Rmax = (long)((avail / rowBytes) / 128) * 128;
  if (Rmax > G) Rmax = G;
  if (Rmax < 128) Rmax = 128;
  u16* Sbuf = (u16*)w;

  if (haveConv) {
    cvt_scale<<<dim3((unsigned)(qsz / 2048)), 256, 0, stream>>>(Q, Qb, qsz, scale);
    cvt_scale<<<dim3((unsigned)(qsz / 2048)), 256, 0, stream>>>(Km, Kb, qsz, 1.0f);
    transcvt_v<<<dim3(S / 64, E / 64, B), 256, 0, stream>>>(V, VTb, (int)S, (int)E);
  }

  for (long g0 = 0; g0 < G; g0 += Rmax) {
    const long R = (G - g0 < Rmax) ? (G - g0) : Rmax;
    if (haveConv) {
      // 1) raw scores = (scale*Q) K^T  (mask deferred to softmax)
      gemm_bf16<0><<<dim3(S / 128, R / 128), 256, 0, stream>>>(
          Qb, (int)E, 0L, Kb, (int)E, S * E,
          Sbuf, (int)S, g0, (int)E, g0, (int)S);
      // 2) softmax(scores + mask) in place
      softmax_rows<1><<<dim3(R), 256, 0, stream>>>(Sbuf, mask, g0, (int)S);
      // 3) out = P V
      gemm_bf16<1><<<dim3(E / 128, R / 128), 256, 0, stream>>>(
          Sbuf, (int)S, g0, VTb, (int)S, E * S,
          out, (int)E, 0L, (int)S, g0, (int)S);
    } else {
      gemm_slow<0, 1, 0><<<dim3(S / 128, R / 128), 256, 0, stream>>>(
          Q, (int)E, 0L, Km, (int)E, S * E,
          Sbuf, (int)S, g0, mask, (int)E, scale, g0, (int)S);
      softmax_rows<0><<<dim3(R), 256, 0, stream>>>(Sbuf, nullptr, g0, (int)S);
      gemm_slow<1, 0, 1><<<dim3(E / 128, R / 128), 256, 0, stream>>>(
          Sbuf, (int)S, g0, V, (int)E, S * E,
          out, (int)E, 0L, nullptr, (int)S, 1.0f, g0, (int)S);
    }
  }
}